// Round 10
// baseline (790.289 us; speedup 1.0000x reference)
//
#include <hip/hip_runtime.h>
#include <math.h>

#define N_NODES 100000
#define N_EDGES 1600000
#define EP (N_EDGES + N_NODES)   // edges + self loops = 1,700,000
#define F 64
#define NB 391                   // ceil(N_NODES / 256)
#define RPW 8                    // rows per wave in k_gemm (100000 % 8 == 0)

// ---- K1: h = X @ W ; asrc = h . aw_s ; adst = h . aw_d ----
// 8 rows per wave -> 8 independent FMA chains per lane; one W load feeds all 8.
__global__ __launch_bounds__(256) void k_gemm(
    const float* __restrict__ X, const float* __restrict__ W,
    const float* __restrict__ aw_s, const float* __restrict__ aw_d,
    float* __restrict__ H, float* __restrict__ asrc, float* __restrict__ adst)
{
    int wid = (blockIdx.x * 256 + threadIdx.x) >> 6;
    int c = threadIdx.x & 63;
    int r0 = wid * RPW;
    if (r0 >= N_NODES) return;

    float xl[RPW], acc[RPW];
#pragma unroll
    for (int i = 0; i < RPW; ++i) {
        xl[i] = X[(size_t)(r0 + i) * F + c];
        acc[i] = 0.f;
    }
#pragma unroll
    for (int k = 0; k < F; ++k) {
        float wv = W[k * F + c];
#pragma unroll
        for (int i = 0; i < RPW; ++i)
            acc[i] = fmaf(__shfl(xl[i], k, 64), wv, acc[i]);
    }
    float ws_ = aw_s[c], wd_ = aw_d[c];
#pragma unroll
    for (int i = 0; i < RPW; ++i) {
        H[(size_t)(r0 + i) * F + c] = acc[i];
        float va = acc[i] * ws_;
        float vd = acc[i] * wd_;
#pragma unroll
        for (int off = 32; off; off >>= 1) {
            va += __shfl_xor(va, off, 64);
            vd += __shfl_xor(vd, off, 64);
        }
        if (c == 0) { asrc[r0 + i] = va; adst[r0 + i] = vd; }
    }
}

// ---- CSR build: histogram of dst + per-edge rank (fused; rank write coalesced) ----
__global__ __launch_bounds__(256) void k_hist(
    const int* __restrict__ edst, int* __restrict__ deg, int* __restrict__ rank)
{
    int e = blockIdx.x * 256 + threadIdx.x;
    if (e >= EP) return;
    int d_ = (e < N_EDGES) ? edst[e] : e - N_EDGES;   // self loops appended
    rank[e] = atomicAdd(deg + d_, 1);
}

// ---- CSR build: per-block partial sums ----
__global__ __launch_bounds__(256) void k_part(
    const int* __restrict__ deg, int* __restrict__ part)
{
    __shared__ int sm[256];
    int t = threadIdx.x;
    int i = blockIdx.x * 256 + t;
    sm[t] = (i < N_NODES) ? deg[i] : 0;
    __syncthreads();
    for (int off = 128; off; off >>= 1) {
        if (t < off) sm[t] += sm[t + off];
        __syncthreads();
    }
    if (t == 0) part[blockIdx.x] = sm[0];
}

// ---- CSR build: scan the 391 block sums (one block) ----
__global__ __launch_bounds__(512) void k_scanpart(
    const int* __restrict__ part, int* __restrict__ poff)
{
    __shared__ int sm[512];
    int t = threadIdx.x;
    int v = (t < NB) ? part[t] : 0;
    sm[t] = v;
    __syncthreads();
    for (int off = 1; off < 512; off <<= 1) {
        int x = (t >= off) ? sm[t - off] : 0;
        __syncthreads();
        sm[t] += x;
        __syncthreads();
    }
    if (t < NB) poff[t] = sm[t] - v;   // exclusive
}

// ---- CSR build: final exclusive scan -> base offsets ----
__global__ __launch_bounds__(256) void k_scanfinal(
    const int* __restrict__ deg, const int* __restrict__ poff, int* __restrict__ base)
{
    __shared__ int sm[256];
    int t = threadIdx.x;
    int i = blockIdx.x * 256 + t;
    int v = (i < N_NODES) ? deg[i] : 0;
    sm[t] = v;
    __syncthreads();
    for (int off = 1; off < 256; off <<= 1) {
        int x = (t >= off) ? sm[t - off] : 0;
        __syncthreads();
        sm[t] += x;
        __syncthreads();
    }
    if (i < N_NODES) base[i] = poff[blockIdx.x] + sm[t] - v;
    if (i == 0) base[N_NODES] = EP;
}

// ---- CSR build: scatter src ids into dst-grouped order (no atomics) ----
__global__ __launch_bounds__(256) void k_scatter(
    const int* __restrict__ esrc, const int* __restrict__ edst,
    const int* __restrict__ base, const int* __restrict__ rank,
    int* __restrict__ ssrc)
{
    int e = blockIdx.x * 256 + threadIdx.x;
    if (e >= EP) return;
    int s_, d_;
    if (e < N_EDGES) { s_ = esrc[e]; d_ = edst[e]; }
    else             { s_ = d_ = e - N_EDGES; }
    ssrc[base[d_] + rank[e]] = s_;
}

// ---- K3: per-node softmax + aggregation + fused finalize. NO atomics. ----
// one wave per node. 4 edges processed concurrently: lane = (group, quad),
// each lane float4-loads 16B of one of 4 H-rows -> 4 row-gathers in flight.
template<bool BN>
__global__ __launch_bounds__(256) void k_aggr(
    const int* __restrict__ base, const int* __restrict__ ssrc,
    const float* __restrict__ asrc, const float* __restrict__ adst,
    const float* __restrict__ H, const float* __restrict__ bias,
    const float* __restrict__ gamma, const float* __restrict__ beta,
    const float* __restrict__ mean, const float* __restrict__ var,
    float* __restrict__ out)
{
    int w = threadIdx.x >> 6, lane = threadIdx.x & 63;
    int n = blockIdx.x * 4 + w;
    if (n >= N_NODES) return;
    int start = base[n], end = base[n + 1];
    float adn = adst[n];

    // phase A: segment max (lane-parallel over edges)
    float mx = -1e30f;
    for (int e = start + lane; e < end; e += 64) {
        float sc = asrc[ssrc[e]] + adn;
        sc = (sc >= 0.f) ? sc : 0.2f * sc;
        mx = fmaxf(mx, sc);
    }
#pragma unroll
    for (int off = 32; off; off >>= 1) mx = fmaxf(mx, __shfl_xor(mx, off, 64));

    // phase B: chunks of 64 edges; weights lane-parallel, then 4-edges-at-a-time
    // broadcast accumulate. Invalid lanes have wg=0, s_=0 -> contribute nothing.
    int g = lane >> 4, q = lane & 15;
    float4 acc = {0.f, 0.f, 0.f, 0.f};
    float ssum = 0.f;
    for (int c = start; c < end; c += 64) {
        int e = c + lane;
        bool v_ = e < end;
        int s_ = v_ ? ssrc[e] : 0;
        float sc = asrc[s_] + adn;
        sc = (sc >= 0.f) ? sc : 0.2f * sc;
        float wg = v_ ? __expf(sc - mx) : 0.f;
        ssum += wg;
        int cnt = min(64, end - c);
        for (int j = 0; j < cnt; j += 4) {
            float wj = __shfl(wg, j + g, 64);
            int   sj = __shfl(s_, j + g, 64);
            const float4 hv = *(const float4*)(H + (size_t)sj * F + q * 4);
            acc.x = fmaf(wj, hv.x, acc.x);
            acc.y = fmaf(wj, hv.y, acc.y);
            acc.z = fmaf(wj, hv.z, acc.z);
            acc.w = fmaf(wj, hv.w, acc.w);
        }
    }
    // reduce acc across the 4 groups; ssum across all 64 lanes
#pragma unroll
    for (int off = 16; off <= 32; off <<= 1) {
        acc.x += __shfl_xor(acc.x, off, 64);
        acc.y += __shfl_xor(acc.y, off, 64);
        acc.z += __shfl_xor(acc.z, off, 64);
        acc.w += __shfl_xor(acc.w, off, 64);
    }
#pragma unroll
    for (int off = 32; off; off >>= 1) ssum += __shfl_xor(ssum, off, 64);

    if (g == 0) {   // 16 lanes store one float4 each -> coalesced 256B row
        float inv = 1.f / (ssum + 1e-16f);
        const float4 bb = ((const float4*)bias)[q];
        float4 o;
        o.x = fmaxf(fmaf(acc.x, inv, bb.x), 0.f);
        o.y = fmaxf(fmaf(acc.y, inv, bb.y), 0.f);
        o.z = fmaxf(fmaf(acc.z, inv, bb.z), 0.f);
        o.w = fmaxf(fmaf(acc.w, inv, bb.w), 0.f);
        if (BN) {
            const float4 gm = ((const float4*)gamma)[q];
            const float4 bt = ((const float4*)beta)[q];
            const float4 mn = ((const float4*)mean)[q];
            const float4 vr = ((const float4*)var)[q];
            o.x = (o.x - mn.x) * rsqrtf(vr.x + 1e-5f) * gm.x + bt.x;
            o.y = (o.y - mn.y) * rsqrtf(vr.y + 1e-5f) * gm.y + bt.y;
            o.z = (o.z - mn.z) * rsqrtf(vr.z + 1e-5f) * gm.z + bt.z;
            o.w = (o.w - mn.w) * rsqrtf(vr.w + 1e-5f) * gm.w + bt.w;
        }
        ((float4*)(out + (size_t)n * F))[q] = o;
    }
}

extern "C" void kernel_launch(void* const* d_in, const int* in_sizes, int n_in,
                              void* d_out, int out_size, void* d_ws, size_t ws_size,
                              hipStream_t stream)
{
    const float* x   = (const float*)d_in[0];
    const int*   adj = (const int*)  d_in[1];
    const float* W1  = (const float*)d_in[2];
    const float* as1 = (const float*)d_in[3];
    const float* ad1 = (const float*)d_in[4];
    const float* b1  = (const float*)d_in[5];
    const float* bng = (const float*)d_in[6];
    const float* bnb = (const float*)d_in[7];
    const float* bnm = (const float*)d_in[8];
    const float* bnv = (const float*)d_in[9];
    const float* W2  = (const float*)d_in[10];
    const float* as2 = (const float*)d_in[11];
    const float* ad2 = (const float*)d_in[12];
    const float* b2  = (const float*)d_in[13];
    float* out = (float*)d_out;

    const int* esrc = adj;
    const int* edst = adj + N_EDGES;

    // workspace layout
    float* ws   = (float*)d_ws;
    float* hA   = ws;                           // N*64: rank (CSR phase), then H1/H2
    float* hB   = hA + (size_t)N_NODES * F;     // N*64: BN(relu(gat1)) = layer-2 input
    float* asrc = hB + (size_t)N_NODES * F;     // N
    float* adst = asrc + N_NODES;               // N
    int*   deg  = (int*)(adst + N_NODES);       // N
    int*   base = deg + N_NODES;                // N+1
    int*   ssrc = base + (N_NODES + 1);         // EP (dst-grouped src ids)
    int*   part = ssrc + EP;                    // NB
    int*   poff = part + NB;                    // NB
    int*   rank = (int*)hA;                     // EP ints, dead before k_gemm writes hA

    dim3 blk(256);
    int gemm_blocks = (N_NODES / RPW * 64) / 256;  // 3125
    int edge_blocks = (EP + 255) / 256;            // 6641
    int node_blocks = (N_NODES + 3) / 4;           // 25000

    // ---- build CSR (dst-bucketed edges), reused by both layers ----
    hipMemsetAsync(deg, 0, N_NODES * 4, stream);
    k_hist     <<<edge_blocks, blk, 0, stream>>>(edst, deg, rank);
    k_part     <<<NB,          blk, 0, stream>>>(deg, part);
    k_scanpart <<<1,           512, 0, stream>>>(part, poff);
    k_scanfinal<<<NB,          blk, 0, stream>>>(deg, poff, base);
    k_scatter  <<<edge_blocks, blk, 0, stream>>>(esrc, edst, base, rank, ssrc);

    // ---- Layer 1 ----
    k_gemm        <<<gemm_blocks, blk, 0, stream>>>(x, W1, as1, ad1, hA, asrc, adst);
    k_aggr<true>  <<<node_blocks, blk, 0, stream>>>(base, ssrc, asrc, adst, hA, b1,
                                                    bng, bnb, bnm, bnv, hB);
    // ---- Layer 2 ----
    k_gemm        <<<gemm_blocks, blk, 0, stream>>>(hB, W2, as2, ad2, hA, asrc, adst);
    k_aggr<false> <<<node_blocks, blk, 0, stream>>>(base, ssrc, asrc, adst, hA, b2,
                                                    nullptr, nullptr, nullptr, nullptr, out);
}

// Round 11
// 397.693 us; speedup vs baseline: 1.9872x; 1.9872x over previous
//
#include <hip/hip_runtime.h>
#include <math.h>

#define N_NODES 100000
#define N_EDGES 1600000
#define EP (N_EDGES + N_NODES)   // edges + self loops = 1,700,000
#define F 64
#define NB 391                   // ceil(N_NODES / 256)
#define GR 16                    // rows per block in k_gemm (100000 % 16 == 0)

// ---- K1: h = X @ W ; asrc = h . aw_s ; adst = h . aw_d ----
// LDS-tiled: W (16KB) + 16 X rows (4KB) staged in LDS. Thread (row=t>>4,
// cg=t&15) computes float4 of outputs. No shfl in k-loop, acc = 4 VGPRs.
__global__ __launch_bounds__(256) void k_gemm(
    const float* __restrict__ X, const float* __restrict__ W,
    const float* __restrict__ aw_s, const float* __restrict__ aw_d,
    float* __restrict__ H, float* __restrict__ asrc, float* __restrict__ adst)
{
    __shared__ float sW[64][64];   // 16 KB
    __shared__ float sX[GR][64];   // 4 KB
    int t = threadIdx.x;
    int r0 = blockIdx.x * GR;

    const float4* W4 = (const float4*)W;
    float4* sW4 = (float4*)sW;
#pragma unroll
    for (int i = 0; i < 4; ++i) sW4[t + i * 256] = W4[t + i * 256];
    ((float4*)sX)[t] = ((const float4*)(X + (size_t)r0 * F))[t];
    __syncthreads();

    int row = t >> 4, cg4 = (t & 15);          // colgroup: cols cg4*4 .. cg4*4+3
    float4 acc = {0.f, 0.f, 0.f, 0.f};
#pragma unroll 8
    for (int k = 0; k < 64; ++k) {
        float xv = sX[row][k];                  // same-addr broadcast (free)
        const float4 wv = *(const float4*)&sW[k][cg4 * 4];
        acc.x = fmaf(xv, wv.x, acc.x);
        acc.y = fmaf(xv, wv.y, acc.y);
        acc.z = fmaf(xv, wv.z, acc.z);
        acc.w = fmaf(xv, wv.w, acc.w);
    }
    ((float4*)(H + (size_t)(r0 + row) * F))[cg4] = acc;   // coalesced

    // attention dot products: partial over this thread's 4 cols, then
    // reduce across the 16 threads of the row (lanes differ only in t&15).
    const float4 as4 = ((const float4*)aw_s)[cg4];
    const float4 ad4 = ((const float4*)aw_d)[cg4];
    float va = acc.x * as4.x + acc.y * as4.y + acc.z * as4.z + acc.w * as4.w;
    float vd = acc.x * ad4.x + acc.y * ad4.y + acc.z * ad4.z + acc.w * ad4.w;
#pragma unroll
    for (int off = 1; off <= 8; off <<= 1) {
        va += __shfl_xor(va, off, 64);
        vd += __shfl_xor(vd, off, 64);
    }
    if ((t & 15) == 0) { asrc[r0 + row] = va; adst[r0 + row] = vd; }
}

// ---- CSR build: histogram of dst + per-edge rank (fused; rank write coalesced) ----
__global__ __launch_bounds__(256) void k_hist(
    const int* __restrict__ edst, int* __restrict__ deg, int* __restrict__ rank)
{
    int e = blockIdx.x * 256 + threadIdx.x;
    if (e >= EP) return;
    int d_ = (e < N_EDGES) ? edst[e] : e - N_EDGES;   // self loops appended
    rank[e] = atomicAdd(deg + d_, 1);
}

// ---- CSR build: per-block partial sums ----
__global__ __launch_bounds__(256) void k_part(
    const int* __restrict__ deg, int* __restrict__ part)
{
    __shared__ int sm[256];
    int t = threadIdx.x;
    int i = blockIdx.x * 256 + t;
    sm[t] = (i < N_NODES) ? deg[i] : 0;
    __syncthreads();
    for (int off = 128; off; off >>= 1) {
        if (t < off) sm[t] += sm[t + off];
        __syncthreads();
    }
    if (t == 0) part[blockIdx.x] = sm[0];
}

// ---- CSR build: scan the 391 block sums (one block) ----
__global__ __launch_bounds__(512) void k_scanpart(
    const int* __restrict__ part, int* __restrict__ poff)
{
    __shared__ int sm[512];
    int t = threadIdx.x;
    int v = (t < NB) ? part[t] : 0;
    sm[t] = v;
    __syncthreads();
    for (int off = 1; off < 512; off <<= 1) {
        int x = (t >= off) ? sm[t - off] : 0;
        __syncthreads();
        sm[t] += x;
        __syncthreads();
    }
    if (t < NB) poff[t] = sm[t] - v;   // exclusive
}

// ---- CSR build: final exclusive scan -> base offsets ----
__global__ __launch_bounds__(256) void k_scanfinal(
    const int* __restrict__ deg, const int* __restrict__ poff, int* __restrict__ base)
{
    __shared__ int sm[256];
    int t = threadIdx.x;
    int i = blockIdx.x * 256 + t;
    int v = (i < N_NODES) ? deg[i] : 0;
    sm[t] = v;
    __syncthreads();
    for (int off = 1; off < 256; off <<= 1) {
        int x = (t >= off) ? sm[t - off] : 0;
        __syncthreads();
        sm[t] += x;
        __syncthreads();
    }
    if (i < N_NODES) base[i] = poff[blockIdx.x] + sm[t] - v;
    if (i == 0) base[N_NODES] = EP;
}

// ---- CSR build: scatter src ids into dst-grouped order (no atomics) ----
__global__ __launch_bounds__(256) void k_scatter(
    const int* __restrict__ esrc, const int* __restrict__ edst,
    const int* __restrict__ base, const int* __restrict__ rank,
    int* __restrict__ ssrc)
{
    int e = blockIdx.x * 256 + threadIdx.x;
    if (e >= EP) return;
    int s_, d_;
    if (e < N_EDGES) { s_ = esrc[e]; d_ = edst[e]; }
    else             { s_ = d_ = e - N_EDGES; }
    ssrc[base[d_] + rank[e]] = s_;
}

// ---- K3: per-node softmax + aggregation + fused finalize. NO atomics. ----
// one wave per node. 4 edges processed concurrently: lane = (group, quad),
// each lane float4-loads 16B of one of 4 H-rows -> 4 row-gathers in flight.
template<bool BN>
__global__ __launch_bounds__(256) void k_aggr(
    const int* __restrict__ base, const int* __restrict__ ssrc,
    const float* __restrict__ asrc, const float* __restrict__ adst,
    const float* __restrict__ H, const float* __restrict__ bias,
    const float* __restrict__ gamma, const float* __restrict__ beta,
    const float* __restrict__ mean, const float* __restrict__ var,
    float* __restrict__ out)
{
    int w = threadIdx.x >> 6, lane = threadIdx.x & 63;
    int n = blockIdx.x * 4 + w;
    if (n >= N_NODES) return;
    int start = base[n], end = base[n + 1];
    float adn = adst[n];

    // phase A: segment max (lane-parallel over edges)
    float mx = -1e30f;
    for (int e = start + lane; e < end; e += 64) {
        float sc = asrc[ssrc[e]] + adn;
        sc = (sc >= 0.f) ? sc : 0.2f * sc;
        mx = fmaxf(mx, sc);
    }
#pragma unroll
    for (int off = 32; off; off >>= 1) mx = fmaxf(mx, __shfl_xor(mx, off, 64));

    // phase B: chunks of 64 edges; weights lane-parallel, then 4-edges-at-a-time
    // broadcast accumulate. Invalid lanes have wg=0, s_=0 -> contribute nothing.
    int g = lane >> 4, q = lane & 15;
    float4 acc = {0.f, 0.f, 0.f, 0.f};
    float ssum = 0.f;
    for (int c = start; c < end; c += 64) {
        int e = c + lane;
        bool v_ = e < end;
        int s_ = v_ ? ssrc[e] : 0;
        float sc = asrc[s_] + adn;
        sc = (sc >= 0.f) ? sc : 0.2f * sc;
        float wg = v_ ? __expf(sc - mx) : 0.f;
        ssum += wg;
        int cnt = min(64, end - c);
        for (int j = 0; j < cnt; j += 4) {
            float wj = __shfl(wg, j + g, 64);
            int   sj = __shfl(s_, j + g, 64);
            const float4 hv = *(const float4*)(H + (size_t)sj * F + q * 4);
            acc.x = fmaf(wj, hv.x, acc.x);
            acc.y = fmaf(wj, hv.y, acc.y);
            acc.z = fmaf(wj, hv.z, acc.z);
            acc.w = fmaf(wj, hv.w, acc.w);
        }
    }
    // reduce acc across the 4 groups; ssum across all 64 lanes
#pragma unroll
    for (int off = 16; off <= 32; off <<= 1) {
        acc.x += __shfl_xor(acc.x, off, 64);
        acc.y += __shfl_xor(acc.y, off, 64);
        acc.z += __shfl_xor(acc.z, off, 64);
        acc.w += __shfl_xor(acc.w, off, 64);
    }
#pragma unroll
    for (int off = 32; off; off >>= 1) ssum += __shfl_xor(ssum, off, 64);

    if (g == 0) {   // 16 lanes store one float4 each -> coalesced 256B row
        float inv = 1.f / (ssum + 1e-16f);
        const float4 bb = ((const float4*)bias)[q];
        float4 o;
        o.x = fmaxf(fmaf(acc.x, inv, bb.x), 0.f);
        o.y = fmaxf(fmaf(acc.y, inv, bb.y), 0.f);
        o.z = fmaxf(fmaf(acc.z, inv, bb.z), 0.f);
        o.w = fmaxf(fmaf(acc.w, inv, bb.w), 0.f);
        if (BN) {
            const float4 gm = ((const float4*)gamma)[q];
            const float4 bt = ((const float4*)beta)[q];
            const float4 mn = ((const float4*)mean)[q];
            const float4 vr = ((const float4*)var)[q];
            o.x = (o.x - mn.x) * rsqrtf(vr.x + 1e-5f) * gm.x + bt.x;
            o.y = (o.y - mn.y) * rsqrtf(vr.y + 1e-5f) * gm.y + bt.y;
            o.z = (o.z - mn.z) * rsqrtf(vr.z + 1e-5f) * gm.z + bt.z;
            o.w = (o.w - mn.w) * rsqrtf(vr.w + 1e-5f) * gm.w + bt.w;
        }
        ((float4*)(out + (size_t)n * F))[q] = o;
    }
}

extern "C" void kernel_launch(void* const* d_in, const int* in_sizes, int n_in,
                              void* d_out, int out_size, void* d_ws, size_t ws_size,
                              hipStream_t stream)
{
    const float* x   = (const float*)d_in[0];
    const int*   adj = (const int*)  d_in[1];
    const float* W1  = (const float*)d_in[2];
    const float* as1 = (const float*)d_in[3];
    const float* ad1 = (const float*)d_in[4];
    const float* b1  = (const float*)d_in[5];
    const float* bng = (const float*)d_in[6];
    const float* bnb = (const float*)d_in[7];
    const float* bnm = (const float*)d_in[8];
    const float* bnv = (const float*)d_in[9];
    const float* W2  = (const float*)d_in[10];
    const float* as2 = (const float*)d_in[11];
    const float* ad2 = (const float*)d_in[12];
    const float* b2  = (const float*)d_in[13];
    float* out = (float*)d_out;

    const int* esrc = adj;
    const int* edst = adj + N_EDGES;

    // workspace layout
    float* ws   = (float*)d_ws;
    float* hA   = ws;                           // N*64: rank (CSR phase), then H1/H2
    float* hB   = hA + (size_t)N_NODES * F;     // N*64: BN(relu(gat1)) = layer-2 input
    float* asrc = hB + (size_t)N_NODES * F;     // N
    float* adst = asrc + N_NODES;               // N
    int*   deg  = (int*)(adst + N_NODES);       // N
    int*   base = deg + N_NODES;                // N+1
    int*   ssrc = base + (N_NODES + 1);         // EP (dst-grouped src ids)
    int*   part = ssrc + EP;                    // NB
    int*   poff = part + NB;                    // NB
    int*   rank = (int*)hA;                     // EP ints, dead before k_gemm writes hA

    dim3 blk(256);
    int gemm_blocks = N_NODES / GR;                // 6250
    int edge_blocks = (EP + 255) / 256;            // 6641
    int node_blocks = (N_NODES + 3) / 4;           // 25000

    // ---- build CSR (dst-bucketed edges), reused by both layers ----
    hipMemsetAsync(deg, 0, N_NODES * 4, stream);
    k_hist     <<<edge_blocks, blk, 0, stream>>>(edst, deg, rank);
    k_part     <<<NB,          blk, 0, stream>>>(deg, part);
    k_scanpart <<<1,           512, 0, stream>>>(part, poff);
    k_scanfinal<<<NB,          blk, 0, stream>>>(deg, poff, base);
    k_scatter  <<<edge_blocks, blk, 0, stream>>>(esrc, edst, base, rank, ssrc);

    // ---- Layer 1 ----
    k_gemm        <<<gemm_blocks, blk, 0, stream>>>(x, W1, as1, ad1, hA, asrc, adst);
    k_aggr<true>  <<<node_blocks, blk, 0, stream>>>(base, ssrc, asrc, adst, hA, b1,
                                                    bng, bnb, bnm, bnv, hB);
    // ---- Layer 2 ----
    k_gemm        <<<gemm_blocks, blk, 0, stream>>>(hB, W2, as2, ad2, hA, asrc, adst);
    k_aggr<false> <<<node_blocks, blk, 0, stream>>>(base, ssrc, asrc, adst, hA, b2,
                                                    nullptr, nullptr, nullptr, nullptr, out);
}